// Round 5
// baseline (6060.235 us; speedup 1.0000x reference)
//
#include <hip/hip_runtime.h>

#define DEV __device__ __forceinline__
typedef unsigned short u16;
typedef __attribute__((ext_vector_type(8))) __bf16 bf16x8;
typedef __attribute__((ext_vector_type(4))) float f32x4;

constexpr int Ln = 12, Nn = 1024, Dn = 768;

DEV float bf2f(u16 u) { unsigned x = ((unsigned)u) << 16; return __builtin_bit_cast(float, x); }
DEV u16 f2bf(float f) {
    unsigned x = __builtin_bit_cast(unsigned, f);
    x = (x + 0x7fffu + ((x >> 16) & 1u)) >> 16;
    return (u16)x;
}

DEV void gll16(const u16* g, u16* l) {
    __builtin_amdgcn_global_load_lds((const __attribute__((address_space(1))) unsigned*)g,
                                     (__attribute__((address_space(3))) unsigned*)l, 16, 0, 0);
}

DEV float block_sum(float v, float* sred) {
#pragma unroll
    for (int o = 32; o > 0; o >>= 1) v += __shfl_down(v, o, 64);
    int wid = threadIdx.x >> 6, lane = threadIdx.x & 63;
    if (lane == 0) sred[wid] = v;
    __syncthreads();
    v = sred[0] + sred[1] + sred[2] + sred[3];
    __syncthreads();
    return v;
}

// ---------------- LN kernels ----------------
__global__ void __launch_bounds__(256) ln1_kernel(
    const float* __restrict__ xf, const u16* __restrict__ xb, float* __restrict__ hbuf,
    const float* __restrict__ temporal, const float* __restrict__ spatial,
    const float* __restrict__ lig, const float* __restrict__ lib,
    const float* __restrict__ lhg, const float* __restrict__ lhb,
    u16* __restrict__ acat, int l, int tF, int tB)
{
    __shared__ float sred[4];
    int r = blockIdx.x, tid = threadIdx.x;
    int dir = r >> 11, b = (r >> 10) & 1, n = r & 1023;
    int t = dir ? tB : tF;
    int tp = dir ? tB : l;      // fwd h-pos uses pos[:, layer]; bwd uses its own time
    int so = (dir * 2 + l) * Dn;
    size_t xoff = ((size_t)(b * Ln + t) * Nn + n) * Dn;
    float* hrow = hbuf + (size_t)r * Dn;
    const float* trt = temporal + (size_t)(b * Ln + t) * Dn;
    const float* trh = temporal + (size_t)(b * Ln + tp) * Dn;
    const float* srow = spatial + (size_t)(b * Nn + n) * Dn;
    u16* arow = acat + (size_t)r * (2 * Dn);

    float xv[3], hv[3], sx = 0.f, sh = 0.f;
#pragma unroll
    for (int i = 0; i < 3; i++) {
        int c = tid + i * 256;
        float sp = srow[c];
        float xr = xf ? xf[xoff + c] : bf2f(xb[xoff + c]);
        xv[i] = xr + trt[c] * sp;
        hv[i] = hrow[c] + trh[c] * sp;
        hrow[c] = hv[i];
        sx += xv[i]; sh += hv[i];
    }
    float mx = block_sum(sx, sred) * (1.f / 768.f);
    float mh = block_sum(sh, sred) * (1.f / 768.f);
    float vx = 0.f, vh = 0.f;
#pragma unroll
    for (int i = 0; i < 3; i++) {
        float d = xv[i] - mx; vx += d * d;
        d = hv[i] - mh; vh += d * d;
    }
    vx = block_sum(vx, sred) * (1.f / 768.f);
    vh = block_sum(vh, sred) * (1.f / 768.f);
    float rx = rsqrtf(vx + 1e-5f), rh = rsqrtf(vh + 1e-5f);
#pragma unroll
    for (int i = 0; i < 3; i++) {
        int c = tid + i * 256;
        arow[c]      = f2bf((xv[i] - mx) * rx * lig[so + c] + lib[so + c]);
        arow[Dn + c] = f2bf((hv[i] - mh) * rh * lhg[so + c] + lhb[so + c]);
    }
}

__global__ void __launch_bounds__(256) ln2_kernel(
    const float* __restrict__ x2, const float* __restrict__ g, const float* __restrict__ bb,
    u16* __restrict__ out, int l)
{
    __shared__ float sred[4];
    int r = blockIdx.x, tid = threadIdx.x;
    int dir = r >> 11;
    int so = (dir * 2 + l) * Dn;
    const float* row = x2 + (size_t)r * Dn;
    u16* orow = out + (size_t)r * Dn;
    float v[3], s = 0.f;
#pragma unroll
    for (int i = 0; i < 3; i++) { int c = tid + i * 256; v[i] = row[c]; s += v[i]; }
    float m = block_sum(s, sred) * (1.f / 768.f);
    float va = 0.f;
#pragma unroll
    for (int i = 0; i < 3; i++) { float d = v[i] - m; va += d * d; }
    va = block_sum(va, sred) * (1.f / 768.f);
    float rs = rsqrtf(va + 1e-5f);
#pragma unroll
    for (int i = 0; i < 3; i++) {
        int c = tid + i * 256;
        orow[c] = f2bf((v[i] - m) * rs * g[so + c] + bb[so + c]);
    }
}

// ---------------- GEMM ----------------
struct GArgs {
    const u16* A; int lda;
    const u16* BT; long long bstride; int ldb; int K;   // cached bf16 B^T
    const float* Wf; const float* Wf2; long long wstride; int ksplit;  // uncached fp32 K-major
    const float* bias1; int b1s;
    const float* bias2; int b2s;
    u16* obf;
    const float* xf; const u16* xb;       // x source (one non-null)
    u16* yb; float* yf; int store_flag;   // y dest (one non-null)
    const float* temp; const float* spat;
    float* x2; float* hbuf;
    int tF, tB;
};

// MODE: 0=QKV (b1+b2, elu+1 cols<1536 -> obf stride 2304)
//       1=O   (plain -> obf stride 768 at col h*64)
//       2=ATTN(bias; x2 = r + x + pos; hbuf += r)
//       3=MLP1(bias; gelu exact -> obf stride 3072)
//       4=MLP2(bias; y = r + x2 -> y store/add at time t)
// CACHED/MODE1 path: double-buffered LDS (NBUF=2, prefetch distance 1, counted
// vmcnt). NBUF=3 REGRESSED (+365us): 48KB LDS cut residency, killing inter-block
// overlap. MT=64 on ATTN/MLP2 (0.75->1.5 blocks/CU) WON -835us: fill dominates
// per-block MFMA:stage ratio. Round 5: extend MT=64 to QKV (2.25->4.5/CU, kills
// 64-block tail) and MLP1 (3->6/CU exact). Duplicated B-reads are L2/L3-resident.
template <int MT, int NT, int MODE, bool CACHED>
__global__ void __launch_bounds__(256) gemm_kernel(GArgs ga)
{
    constexpr int FM = MT / 32, FN = NT / 32;
    constexpr bool DB = (CACHED || MODE == 1);
    constexpr int NBUF = DB ? 2 : 1;
    __shared__ __align__(16) u16 As[NBUF][MT * 32];
    __shared__ __align__(16) u16 Bs[NBUF][NT * 32];
    int tid = threadIdx.x;
    const u16 *A, *Bc = nullptr;
    const float *W1_ = nullptr, *W2_ = nullptr;
    int lda, ldb, K, rowbase, colbase, dir = 0;
    if constexpr (MODE == 1) {
        int combo = blockIdx.y, g4 = combo / 12, h = combo - g4 * 12;
        rowbase = g4 * 1024 + blockIdx.x * MT; colbase = h * 64;
        A = ga.A + (size_t)rowbase * 2304 + h * 64; lda = 2304;
        Bc = ga.BT + (size_t)combo * 4096; ldb = 64; K = 64;
    } else {
        dir = blockIdx.z;
        rowbase = dir * 2048 + blockIdx.x * MT; colbase = blockIdx.y * NT;
        A = ga.A + (size_t)rowbase * ga.lda; lda = ga.lda;
        ldb = ga.ldb; K = ga.K;
        if constexpr (CACHED) {
            Bc = ga.BT + (size_t)dir * ga.bstride + (size_t)colbase * ldb;
        } else {
            W1_ = ga.Wf + (size_t)dir * ga.wstride + colbase;
            if (ga.Wf2) W2_ = ga.Wf2 + (size_t)dir * ga.wstride + colbase;
        }
    }
    int wid = tid >> 6, lane = tid & 63;
    int wm = wid >> 1, wn = wid & 1, lrow = lane & 15, kq = lane >> 4;
    f32x4 acc[FM][FN];
#pragma unroll
    for (int i = 0; i < FM; i++)
#pragma unroll
        for (int j = 0; j < FN; j++) acc[i][j] = f32x4{0.f, 0.f, 0.f, 0.f};

    if constexpr (DB) {
        constexpr int AL = (MT * 64) / 4096;
        constexpr int BL = (NT * 64) / 4096;
        constexpr int LPS = AL + BL;   // gll16s in flight per stage per thread
        auto stage = [&](int buf, int k0) {
#pragma unroll
            for (int p = 0; p < AL; p++) {
                int idx = p * 256 + tid, row = idx >> 2, ch = idx & 3;
                gll16(A + (size_t)row * lda + k0 + ch * 8, As[buf] + idx * 8);
            }
#pragma unroll
            for (int p = 0; p < BL; p++) {
                int idx = p * 256 + tid, row = idx >> 2, ch = idx & 3;
                gll16(Bc + (size_t)row * ldb + k0 + ch * 8, Bs[buf] + idx * 8);
            }
        };
        stage(0, 0);
        const int nk = K >> 5;
        for (int t = 0; t < nk; t++) {
            int cur = t & 1;
            if (t + 1 < nk) {
                stage(cur ^ 1, (t + 1) << 5);
                // wait only for the CURRENT buffer's loads; keep next tile's
                // LPS loads in flight across the barrier (counted vmcnt, T4)
                asm volatile("s_waitcnt vmcnt(%0)" :: "n"(LPS) : "memory");
            } else {
                asm volatile("s_waitcnt vmcnt(0)" ::: "memory");
            }
            __builtin_amdgcn_s_barrier();
            asm volatile("" ::: "memory");   // pin ds_reads below the barrier
            bf16x8 av[FM], bv[FN];
#pragma unroll
            for (int i = 0; i < FM; i++)
                av[i] = *(const bf16x8*)(As[cur] + (wm * (MT / 2) + i * 16 + lrow) * 32 + kq * 8);
#pragma unroll
            for (int j = 0; j < FN; j++)
                bv[j] = *(const bf16x8*)(Bs[cur] + (wn * (NT / 2) + j * 16 + lrow) * 32 + kq * 8);
#pragma unroll
            for (int i = 0; i < FM; i++)
#pragma unroll
                for (int j = 0; j < FN; j++)
                    acc[i][j] = __builtin_amdgcn_mfma_f32_16x16x32_bf16(av[i], bv[j], acc[i][j], 0, 0, 0);
            asm volatile("" ::: "memory");   // pin next-iter stage below this barrier
            __builtin_amdgcn_s_barrier();
        }
    } else {
        for (int k0 = 0; k0 < K; k0 += 32) {
#pragma unroll
            for (int p = 0; p < (MT * 64) / 4096; p++) {
                int idx = p * 256 + tid, row = idx >> 2, ch = idx & 3;
                gll16(A + (size_t)row * lda + k0 + ch * 8, As[0] + idx * 8);
            }
            {
                const float* Wk = (W2_ && k0 >= ga.ksplit) ? W2_ + (size_t)(k0 - ga.ksplit) * ldb
                                                           : W1_ + (size_t)k0 * ldb;
#pragma unroll
                for (int p = 0; p < NT / 32; p++) {
                    int u = p * 256 + tid;
                    int k = u >> 5, nb = u & 31;
                    float4 w = *(const float4*)(Wk + (size_t)k * ldb + nb * 4);
                    Bs[0][(nb * 4 + 0) * 32 + k] = f2bf(w.x);
                    Bs[0][(nb * 4 + 1) * 32 + k] = f2bf(w.y);
                    Bs[0][(nb * 4 + 2) * 32 + k] = f2bf(w.z);
                    Bs[0][(nb * 4 + 3) * 32 + k] = f2bf(w.w);
                }
            }
            __syncthreads();
            bf16x8 av[FM], bv[FN];
#pragma unroll
            for (int i = 0; i < FM; i++)
                av[i] = *(const bf16x8*)(As[0] + (wm * (MT / 2) + i * 16 + lrow) * 32 + kq * 8);
#pragma unroll
            for (int j = 0; j < FN; j++)
                bv[j] = *(const bf16x8*)(Bs[0] + (wn * (NT / 2) + j * 16 + lrow) * 32 + kq * 8);
#pragma unroll
            for (int i = 0; i < FM; i++)
#pragma unroll
                for (int j = 0; j < FN; j++)
                    acc[i][j] = __builtin_amdgcn_mfma_f32_16x16x32_bf16(av[i], bv[j], acc[i][j], 0, 0, 0);
            __syncthreads();
        }
    }

    const float* b1 = ga.bias1 ? ga.bias1 + (size_t)dir * ga.b1s : nullptr;
    const float* b2 = ga.bias2 ? ga.bias2 + (size_t)dir * ga.b2s : nullptr;
#pragma unroll
    for (int fm = 0; fm < FM; fm++) {
#pragma unroll
        for (int fn = 0; fn < FN; fn++) {
#pragma unroll
            for (int r2 = 0; r2 < 4; r2++) {
                int row = rowbase + wm * (MT / 2) + fm * 16 + kq * 4 + r2;
                int col = colbase + wn * (NT / 2) + fn * 16 + lrow;
                float v = acc[fm][fn][r2];
                if constexpr (MODE == 0) {
                    v += b1[col] + b2[col];
                    if (col < 1536) v = v > 0.f ? v + 1.f : __expf(v);
                    ga.obf[(size_t)row * 2304 + col] = f2bf(v);
                } else if constexpr (MODE == 1) {
                    ga.obf[(size_t)row * 768 + col] = f2bf(v);
                } else if constexpr (MODE == 2) {
                    v += b1[col];
                    int b = (row >> 10) & 1, n = row & 1023;
                    int t = (row >> 11) ? ga.tB : ga.tF;
                    float pos = ga.temp[(size_t)(b * Ln + t) * Dn + col] *
                                ga.spat[(size_t)(b * Nn + n) * Dn + col];
                    size_t xi = ((size_t)(b * Ln + t) * Nn + n) * Dn + col;
                    float xv = (ga.xf ? ga.xf[xi] : bf2f(ga.xb[xi])) + pos;
                    ga.x2[(size_t)row * Dn + col] = v + xv;
                    ga.hbuf[(size_t)row * Dn + col] += v;
                } else if constexpr (MODE == 3) {
                    v += b1[col];
                    v = 0.5f * v * (1.f + erff(v * 0.7071067811865475f));
                    ga.obf[(size_t)row * 3072 + col] = f2bf(v);
                } else {
                    v += b1[col] + ga.x2[(size_t)row * Dn + col];
                    int b = (row >> 10) & 1, n = row & 1023;
                    int t = (row >> 11) ? ga.tB : ga.tF;
                    size_t oi = ((size_t)(b * Ln + t) * Nn + n) * Dn + col;
                    if (ga.yf) {
                        if (ga.store_flag) ga.yf[oi] = v;
                        else ga.yf[oi] += v;
                    } else {
                        if (ga.store_flag) ga.yb[oi] = f2bf(v);
                        else ga.yb[oi] = f2bf(v + bf2f(ga.yb[oi]));
                    }
                }
            }
        }
    }
}

// ---------------- kv einsum ----------------
__global__ void __launch_bounds__(256) kv_partial_kernel(const u16* __restrict__ qkv,
                                                         float* __restrict__ part)
{
    int combo = blockIdx.x, js = blockIdx.y;
    int g4 = combo / 12, h = combo - g4 * 12;
    int d0 = (threadIdx.x & 15) * 4, e0 = (threadIdx.x >> 4) * 4;
    const u16* base = qkv + ((size_t)g4 * 1024 + js * 128) * 2304 + 768 + h * 64;
    float acc[4][4] = {};
#pragma unroll 4
    for (int j = 0; j < 128; j++) {
        const u16* kp = base + (size_t)j * 2304 + d0;
        const u16* vp = base + (size_t)j * 2304 + 768 + e0;
        ushort4 kk = *(const ushort4*)kp;
        ushort4 vv = *(const ushort4*)vp;
        float kd[4] = {bf2f(kk.x), bf2f(kk.y), bf2f(kk.z), bf2f(kk.w)};
        float ve[4] = {bf2f(vv.x), bf2f(vv.y), bf2f(vv.z), bf2f(vv.w)};
#pragma unroll
        for (int di = 0; di < 4; di++)
#pragma unroll
            for (int ei = 0; ei < 4; ei++) acc[di][ei] += kd[di] * ve[ei];
    }
    float* pp = part + ((size_t)js * 48 + combo) * 4096;
#pragma unroll
    for (int di = 0; di < 4; di++)
#pragma unroll
        for (int ei = 0; ei < 4; ei++)
            pp[(e0 + ei) * 64 + (d0 + di)] = acc[di][ei];   // kv^T: [e][d]
}

__global__ void __launch_bounds__(256) kv_reduce_kernel(const float* __restrict__ part,
                                                        u16* __restrict__ kvT)
{
    int combo = blockIdx.x;
    for (int idx = threadIdx.x; idx < 4096; idx += 256) {
        float s = 0.f;
#pragma unroll
        for (int js = 0; js < 8; js++) s += part[((size_t)js * 48 + combo) * 4096 + idx];
        kvT[(size_t)combo * 4096 + idx] = f2bf(s);
    }
}

// ---------------- weight transpose (fp32 -> bf16 B^T) ----------------
__global__ void transpose_kernel(const float* __restrict__ src, u16* __restrict__ dst,
                                 int K, int N, int ldd, int dcol)
{
    __shared__ float tile[32][33];
    int n0 = blockIdx.x * 32, k0 = blockIdx.y * 32;
    int tx = threadIdx.x, ty = threadIdx.y;   // (32,8)
#pragma unroll
    for (int i = 0; i < 4; i++) {
        int k = k0 + ty + i * 8;
        tile[ty + i * 8][tx] = src[(size_t)k * N + n0 + tx];
    }
    __syncthreads();
#pragma unroll
    for (int i = 0; i < 4; i++) {
        int n = n0 + ty + i * 8;
        dst[(size_t)n * ldd + dcol + k0 + tx] = f2bf(tile[tx][ty + i * 8]);
    }
}

__global__ void __launch_bounds__(256) init_h_kernel(const float* __restrict__ hidden,
                                                     float* __restrict__ hbuf)
{
    unsigned i = blockIdx.x * 256u + threadIdx.x;   // 4*1024*768
    unsigned d = i % 768u;
    unsigned r = i / 768u;
    unsigned b = (r >> 10) & 1u, n = r & 1023u;
    hbuf[i] = hidden[((size_t)b * 1024 + n) * 768 + d];
}

// ---------------- host ----------------
extern "C" void kernel_launch(void* const* d_in, const int* in_sizes, int n_in,
                              void* d_out, int out_size, void* d_ws, size_t ws_size,
                              hipStream_t stream)
{
    (void)in_sizes; (void)n_in; (void)out_size;
    const float* xin    = (const float*)d_in[0];
    const float* hidden = (const float*)d_in[1];
    const float* spat   = (const float*)d_in[2];
    const float* temp   = (const float*)d_in[3];
    const float* lig    = (const float*)d_in[4];
    const float* lib_   = (const float*)d_in[5];
    const float* lhg    = (const float*)d_in[6];
    const float* lhb    = (const float*)d_in[7];
    const float* log_   = (const float*)d_in[8];
    const float* lob    = (const float*)d_in[9];
    const float* Wqkv   = (const float*)d_in[10];
    const float* bqkv   = (const float*)d_in[11];
    const float* Wqkvh  = (const float*)d_in[12];
    const float* bqkvh  = (const float*)d_in[13];
    const float* Wout   = (const float*)d_in[14];
    const float* bout   = (const float*)d_in[15];
    const float* W1     = (const float*)d_in[16];
    const float* b1     = (const float*)d_in[17];
    const float* W2     = (const float*)d_in[18];
    const float* b2     = (const float*)d_in[19];

    char* w = (char*)d_ws;
    float* hbuf  = (float*)(w + 0);              // 12,582,912 B
    float* x2    = (float*)(w + 12582912);       // 12,582,912 B
    u16*   xC    = (u16*)(w + 25165824);         // 37,748,736 B (bf16 layer-0 output)
    u16*   kvT   = (u16*)(w + 62914560);         //    393,216 B
    u16*   regA  = (u16*)(w + 63307776);         // 12,582,912 B
    u16*   regB  = (u16*)(w + 75890688);         // 25,165,824 B  -> base end 101,056,512
    u16*   qkvTc = (u16*)(w + 101056512);        // 14,155,776 B
    u16*   woutTc= (u16*)(w + 115212288);        //  2,359,296 B
    u16*   w1Tc  = (u16*)(w + 117571584);        //  9,437,184 B
    u16*   w2Tc  = (u16*)(w + 127008768);        //  9,437,184 B  -> 136,445,952
    const bool cached = ws_size >= 136445952ull;

    u16*   acat  = regA;
    float* kvp   = (float*)regA;                 // alias after acat dead
    u16*   obf   = regA;                         // alias after kvp dead
    u16*   ln2b  = regA + 3145728;               // second half of regA
    u16*   qkvb  = regB;
    u16*   mlp1b = regB;

    dim3 tb(32, 8);
    for (int l = 0; l < 2; l++) {
        if (cached) {
            for (int dir = 0; dir < 2; dir++) {
                int s4 = dir * 2 + l;
                transpose_kernel<<<dim3(72, 24), tb, 0, stream>>>(
                    Wqkv + (size_t)s4 * 768 * 2304, qkvTc + (size_t)dir * 2304 * 1536, 768, 2304, 1536, 0);
                transpose_kernel<<<dim3(72, 24), tb, 0, stream>>>(
                    Wqkvh + (size_t)s4 * 768 * 2304, qkvTc + (size_t)dir * 2304 * 1536, 768, 2304, 1536, 768);
                transpose_kernel<<<dim3(24, 24), tb, 0, stream>>>(
                    Wout + (size_t)s4 * 768 * 768, woutTc + (size_t)dir * 768 * 768, 768, 768, 768, 0);
                transpose_kernel<<<dim3(96, 24), tb, 0, stream>>>(
                    W1 + (size_t)s4 * 768 * 3072, w1Tc + (size_t)dir * 3072 * 768, 768, 3072, 768, 0);
                transpose_kernel<<<dim3(24, 96), tb, 0, stream>>>(
                    W2 + (size_t)s4 * 3072 * 768, w2Tc + (size_t)dir * 768 * 3072, 3072, 768, 3072, 0);
            }
        }
        init_h_kernel<<<12288, 256, 0, stream>>>(hidden, hbuf);
        const float* xsf = l ? nullptr : xin;
        const u16*   xsb = l ? xC : nullptr;
        float* yf = l ? (float*)d_out : nullptr;
        u16*   yb = l ? nullptr : xC;
        for (int s = 0; s < 12; s++) {
            int tF = s, tB = 11 - s;
            ln1_kernel<<<4096, 256, 0, stream>>>(xsf, xsb, hbuf, temp, spat, lig, lib_, lhg, lhb,
                                                 acat, l, tF, tB);
            {   // QKV  (MT=64: 1152 blocks, 4.5/CU)
                GArgs g{};
                g.A = acat; g.lda = 1536; g.K = 1536;
                g.bias1 = bqkv + (size_t)l * 2304; g.b1s = 2 * 2304;
                g.bias2 = bqkvh + (size_t)l * 2304; g.b2s = 2 * 2304;
                g.obf = qkvb;
                if (cached) {
                    g.BT = qkvTc; g.bstride = 2304ll * 1536; g.ldb = 1536;
                    gemm_kernel<64, 128, 0, true><<<dim3(32, 18, 2), 256, 0, stream>>>(g);
                } else {
                    g.Wf = Wqkv + (size_t)l * 768 * 2304;
                    g.Wf2 = Wqkvh + (size_t)l * 768 * 2304;
                    g.wstride = 2ll * 768 * 2304; g.ksplit = 768; g.ldb = 2304;
                    gemm_kernel<64, 128, 0, false><<<dim3(32, 18, 2), 256, 0, stream>>>(g);
                }
            }
            kv_partial_kernel<<<dim3(48, 8), 256, 0, stream>>>(qkvb, kvp);
            kv_reduce_kernel<<<48, 256, 0, stream>>>(kvp, kvT);
            {   // O = q . kv
                GArgs g{};
                g.A = qkvb; g.BT = kvT; g.obf = obf;
                gemm_kernel<128, 64, 1, true><<<dim3(8, 48, 1), 256, 0, stream>>>(g);
            }
            {   // attn out + residual + hidden update  (MT=64: 384 blocks, 1.5/CU)
                GArgs g{};
                g.A = obf; g.lda = 768; g.K = 768;
                g.bias1 = bout + (size_t)l * 768; g.b1s = 2 * 768;
                g.xf = xsf; g.xb = xsb; g.temp = temp; g.spat = spat; g.x2 = x2; g.hbuf = hbuf;
                g.tF = tF; g.tB = tB;
                if (cached) {
                    g.BT = woutTc; g.bstride = 768ll * 768; g.ldb = 768;
                    gemm_kernel<64, 128, 2, true><<<dim3(32, 6, 2), 256, 0, stream>>>(g);
                } else {
                    g.Wf = Wout + (size_t)l * 768 * 768; g.wstride = 2ll * 768 * 768;
                    g.ldb = 768; g.ksplit = g.K;
                    gemm_kernel<64, 128, 2, false><<<dim3(32, 6, 2), 256, 0, stream>>>(g);
                }
            }
            ln2_kernel<<<4096, 256, 0, stream>>>(x2, log_, lob, ln2b, l);
            {   // MLP1  (MT=64: 1536 blocks, 6/CU)
                GArgs g{};
                g.A = ln2b; g.lda = 768; g.K = 768;
                g.bias1 = b1 + (size_t)l * 3072; g.b1s = 2 * 3072;
                g.obf = mlp1b;
                if (cached) {
                    g.BT = w1Tc; g.bstride = 3072ll * 768; g.ldb = 768;
                    gemm_kernel<64, 128, 3, true><<<dim3(32, 24, 2), 256, 0, stream>>>(g);
                } else {
                    g.Wf = W1 + (size_t)l * 768 * 3072; g.wstride = 2ll * 768 * 3072;
                    g.ldb = 3072; g.ksplit = g.K;
                    gemm_kernel<64, 128, 3, false><<<dim3(32, 24, 2), 256, 0, stream>>>(g);
                }
            }
            {   // MLP2 + residual -> y accumulate  (MT=64: 384 blocks, 1.5/CU)
                GArgs g{};
                g.A = mlp1b; g.lda = 3072; g.K = 3072;
                g.bias1 = b2 + (size_t)l * 768; g.b1s = 2 * 768;
                g.x2 = x2; g.yf = yf; g.yb = yb; g.store_flag = (s <= 5) ? 1 : 0;
                g.tF = tF; g.tB = tB;
                if (cached) {
                    g.BT = w2Tc; g.bstride = 768ll * 3072; g.ldb = 3072;
                    gemm_kernel<64, 128, 4, true><<<dim3(32, 6, 2), 256, 0, stream>>>(g);
                } else {
                    g.Wf = W2 + (size_t)l * 3072 * 768; g.wstride = 2ll * 3072 * 768;
                    g.ldb = 768; g.ksplit = g.K;
                    gemm_kernel<64, 128, 4, false><<<dim3(32, 6, 2), 256, 0, stream>>>(g);
                }
            }
        }
    }
}

// Round 6
// 5591.389 us; speedup vs baseline: 1.0839x; 1.0839x over previous
//
#include <hip/hip_runtime.h>

#define DEV __device__ __forceinline__
typedef unsigned short u16;
typedef __attribute__((ext_vector_type(8))) __bf16 bf16x8;
typedef __attribute__((ext_vector_type(4))) float f32x4;

constexpr int Ln = 12, Nn = 1024, Dn = 768;

DEV float bf2f(u16 u) { unsigned x = ((unsigned)u) << 16; return __builtin_bit_cast(float, x); }
DEV u16 f2bf(float f) {
    unsigned x = __builtin_bit_cast(unsigned, f);
    x = (x + 0x7fffu + ((x >> 16) & 1u)) >> 16;
    return (u16)x;
}

DEV void gll16(const u16* g, u16* l) {
    __builtin_amdgcn_global_load_lds((const __attribute__((address_space(1))) unsigned*)g,
                                     (__attribute__((address_space(3))) unsigned*)l, 16, 0, 0);
}

DEV float wave_sum(float v) {
#pragma unroll
    for (int o = 32; o > 0; o >>= 1) v += __shfl_xor(v, o, 64);
    return v;
}

// ---------------- LN kernels (wave-per-row, float4 vectorized; G13) ----------------
__global__ void __launch_bounds__(256) ln1_kernel(
    const float* __restrict__ xf, const u16* __restrict__ xb, float* __restrict__ hbuf,
    const float* __restrict__ temporal, const float* __restrict__ spatial,
    const float* __restrict__ lig, const float* __restrict__ lib,
    const float* __restrict__ lhg, const float* __restrict__ lhb,
    u16* __restrict__ acat, int l, int tF, int tB)
{
    int wv = threadIdx.x >> 6, lane = threadIdx.x & 63;
    int r = blockIdx.x * 4 + wv;
    int dir = r >> 11, b = (r >> 10) & 1, n = r & 1023;
    int t = dir ? tB : tF;
    int tp = dir ? tB : l;      // fwd h-pos uses pos[:, layer]; bwd uses its own time
    int so = (dir * 2 + l) * Dn;
    size_t xoff = ((size_t)(b * Ln + t) * Nn + n) * Dn;
    float* hrow = hbuf + (size_t)r * Dn;
    const float* trt = temporal + (size_t)(b * Ln + t) * Dn;
    const float* trh = temporal + (size_t)(b * Ln + tp) * Dn;
    const float* srow = spatial + (size_t)(b * Nn + n) * Dn;
    u16* arow = acat + (size_t)r * (2 * Dn);

    float xv[3][4], hv[3][4], sx = 0.f, sh = 0.f;
#pragma unroll
    for (int j = 0; j < 3; j++) {
        int c = j * 256 + lane * 4;
        float4 sp = *(const float4*)(srow + c);
        float4 tt = *(const float4*)(trt + c);
        float4 th = *(const float4*)(trh + c);
        float4 hr = *(const float4*)(hrow + c);
        float spv[4] = {sp.x, sp.y, sp.z, sp.w};
        float ttv[4] = {tt.x, tt.y, tt.z, tt.w};
        float thv[4] = {th.x, th.y, th.z, th.w};
        float hrv[4] = {hr.x, hr.y, hr.z, hr.w};
        float xr[4];
        if (xf) {
            float4 xx = *(const float4*)(xf + xoff + c);
            xr[0] = xx.x; xr[1] = xx.y; xr[2] = xx.z; xr[3] = xx.w;
        } else {
            ushort4 xx = *(const ushort4*)(xb + xoff + c);
            xr[0] = bf2f(xx.x); xr[1] = bf2f(xx.y); xr[2] = bf2f(xx.z); xr[3] = bf2f(xx.w);
        }
#pragma unroll
        for (int k = 0; k < 4; k++) {
            xv[j][k] = xr[k] + ttv[k] * spv[k];
            hv[j][k] = hrv[k] + thv[k] * spv[k];
            sx += xv[j][k]; sh += hv[j][k];
        }
        *(float4*)(hrow + c) = float4{hv[j][0], hv[j][1], hv[j][2], hv[j][3]};
    }
    float mx = wave_sum(sx) * (1.f / 768.f);
    float mh = wave_sum(sh) * (1.f / 768.f);
    float vx = 0.f, vh = 0.f;
#pragma unroll
    for (int j = 0; j < 3; j++)
#pragma unroll
        for (int k = 0; k < 4; k++) {
            float d = xv[j][k] - mx; vx += d * d;
            d = hv[j][k] - mh; vh += d * d;
        }
    vx = wave_sum(vx) * (1.f / 768.f);
    vh = wave_sum(vh) * (1.f / 768.f);
    float rx = rsqrtf(vx + 1e-5f), rh = rsqrtf(vh + 1e-5f);
#pragma unroll
    for (int j = 0; j < 3; j++) {
        int c = j * 256 + lane * 4;
        float4 g1 = *(const float4*)(lig + so + c);
        float4 b1 = *(const float4*)(lib + so + c);
        float4 g2 = *(const float4*)(lhg + so + c);
        float4 b2 = *(const float4*)(lhb + so + c);
        float g1v[4] = {g1.x, g1.y, g1.z, g1.w}, b1v[4] = {b1.x, b1.y, b1.z, b1.w};
        float g2v[4] = {g2.x, g2.y, g2.z, g2.w}, b2v[4] = {b2.x, b2.y, b2.z, b2.w};
        ushort4 oa, ob;
        u16* pa = (u16*)&oa; u16* pb = (u16*)&ob;
#pragma unroll
        for (int k = 0; k < 4; k++) {
            pa[k] = f2bf((xv[j][k] - mx) * rx * g1v[k] + b1v[k]);
            pb[k] = f2bf((hv[j][k] - mh) * rh * g2v[k] + b2v[k]);
        }
        *(ushort4*)(arow + c) = oa;
        *(ushort4*)(arow + Dn + c) = ob;
    }
}

__global__ void __launch_bounds__(256) ln2_kernel(
    const float* __restrict__ x2, const float* __restrict__ g, const float* __restrict__ bb,
    u16* __restrict__ out, int l)
{
    int wv = threadIdx.x >> 6, lane = threadIdx.x & 63;
    int r = blockIdx.x * 4 + wv;
    int dir = r >> 11;
    int so = (dir * 2 + l) * Dn;
    const float* row = x2 + (size_t)r * Dn;
    u16* orow = out + (size_t)r * Dn;
    float v[3][4], s = 0.f;
#pragma unroll
    for (int j = 0; j < 3; j++) {
        int c = j * 256 + lane * 4;
        float4 x = *(const float4*)(row + c);
        v[j][0] = x.x; v[j][1] = x.y; v[j][2] = x.z; v[j][3] = x.w;
        s += v[j][0] + v[j][1] + v[j][2] + v[j][3];
    }
    float m = wave_sum(s) * (1.f / 768.f);
    float va = 0.f;
#pragma unroll
    for (int j = 0; j < 3; j++)
#pragma unroll
        for (int k = 0; k < 4; k++) { float d = v[j][k] - m; va += d * d; }
    va = wave_sum(va) * (1.f / 768.f);
    float rs = rsqrtf(va + 1e-5f);
#pragma unroll
    for (int j = 0; j < 3; j++) {
        int c = j * 256 + lane * 4;
        float4 gg = *(const float4*)(g + so + c);
        float4 bv = *(const float4*)(bb + so + c);
        float gv[4] = {gg.x, gg.y, gg.z, gg.w}, bbv[4] = {bv.x, bv.y, bv.z, bv.w};
        ushort4 o; u16* po = (u16*)&o;
#pragma unroll
        for (int k = 0; k < 4; k++) po[k] = f2bf((v[j][k] - m) * rs * gv[k] + bbv[k]);
        *(ushort4*)(orow + c) = o;
    }
}

// ---------------- GEMM ----------------
struct GArgs {
    const u16* A; int lda;
    const u16* BT; long long bstride; int ldb; int K;   // cached bf16 B^T
    const float* Wf; const float* Wf2; long long wstride; int ksplit;  // uncached fp32 K-major
    const float* bias1; int b1s;
    const float* bias2; int b2s;
    u16* obf;
    const float* xf; const u16* xb;       // x source (one non-null)
    u16* yb; float* yf; int store_flag;   // y dest (one non-null)
    const float* temp; const float* spat;
    float* x2; float* hbuf;
    int tF, tB;
};

// MODE: 0=QKV (b1+b2, elu+1 cols<1536 -> obf stride 2304)
//       1=O   (plain -> obf stride 768 at col h*64)
//       2=ATTN(bias; x2 = r + x + pos; hbuf += r)
//       3=MLP1(bias; gelu exact -> obf stride 3072)
//       4=MLP2(bias; y = r + x2 -> y store/add at time t)
// Tuning history (measured):
//  - NBUF=2 + counted vmcnt: -460us vs drain-0 baseline. NBUF=3 REGRESSED (+365us,
//    48KB LDS cut residency). Keep NBUF=2.
//  - MT=64 on ATTN/MLP2 (0.75->1.5 blk/CU): WON -835us. MT=64 on QKV/MLP1
//    (2.25/3.0 -> 4.5/6.0): REGRESSED +372us. Rule: MT=64 only below ~2 blk/CU.
template <int MT, int NT, int MODE, bool CACHED>
__global__ void __launch_bounds__(256) gemm_kernel(GArgs ga)
{
    constexpr int FM = MT / 32, FN = NT / 32;
    constexpr bool DB = (CACHED || MODE == 1);
    constexpr int NBUF = DB ? 2 : 1;
    __shared__ __align__(16) u16 As[NBUF][MT * 32];
    __shared__ __align__(16) u16 Bs[NBUF][NT * 32];
    int tid = threadIdx.x;
    const u16 *A, *Bc = nullptr;
    const float *W1_ = nullptr, *W2_ = nullptr;
    int lda, ldb, K, rowbase, colbase, dir = 0;
    if constexpr (MODE == 1) {
        int combo = blockIdx.y, g4 = combo / 12, h = combo - g4 * 12;
        rowbase = g4 * 1024 + blockIdx.x * MT; colbase = h * 64;
        A = ga.A + (size_t)rowbase * 2304 + h * 64; lda = 2304;
        Bc = ga.BT + (size_t)combo * 4096; ldb = 64; K = 64;
    } else {
        dir = blockIdx.z;
        rowbase = dir * 2048 + blockIdx.x * MT; colbase = blockIdx.y * NT;
        A = ga.A + (size_t)rowbase * ga.lda; lda = ga.lda;
        ldb = ga.ldb; K = ga.K;
        if constexpr (CACHED) {
            Bc = ga.BT + (size_t)dir * ga.bstride + (size_t)colbase * ldb;
        } else {
            W1_ = ga.Wf + (size_t)dir * ga.wstride + colbase;
            if (ga.Wf2) W2_ = ga.Wf2 + (size_t)dir * ga.wstride + colbase;
        }
    }
    int wid = tid >> 6, lane = tid & 63;
    int wm = wid >> 1, wn = wid & 1, lrow = lane & 15, kq = lane >> 4;
    f32x4 acc[FM][FN];
#pragma unroll
    for (int i = 0; i < FM; i++)
#pragma unroll
        for (int j = 0; j < FN; j++) acc[i][j] = f32x4{0.f, 0.f, 0.f, 0.f};

    if constexpr (DB) {
        constexpr int AL = (MT * 64) / 4096;
        constexpr int BL = (NT * 64) / 4096;
        constexpr int LPS = AL + BL;   // gll16s in flight per stage per thread
        auto stage = [&](int buf, int k0) {
#pragma unroll
            for (int p = 0; p < AL; p++) {
                int idx = p * 256 + tid, row = idx >> 2, ch = idx & 3;
                gll16(A + (size_t)row * lda + k0 + ch * 8, As[buf] + idx * 8);
            }
#pragma unroll
            for (int p = 0; p < BL; p++) {
                int idx = p * 256 + tid, row = idx >> 2, ch = idx & 3;
                gll16(Bc + (size_t)row * ldb + k0 + ch * 8, Bs[buf] + idx * 8);
            }
        };
        stage(0, 0);
        const int nk = K >> 5;
        for (int t = 0; t < nk; t++) {
            int cur = t & 1;
            if (t + 1 < nk) {
                stage(cur ^ 1, (t + 1) << 5);
                // wait only for the CURRENT buffer's loads; keep next tile's
                // LPS loads in flight across the barrier (counted vmcnt, T4)
                asm volatile("s_waitcnt vmcnt(%0)" :: "n"(LPS) : "memory");
            } else {
                asm volatile("s_waitcnt vmcnt(0)" ::: "memory");
            }
            __builtin_amdgcn_s_barrier();
            asm volatile("" ::: "memory");   // pin ds_reads below the barrier
            bf16x8 av[FM], bv[FN];
#pragma unroll
            for (int i = 0; i < FM; i++)
                av[i] = *(const bf16x8*)(As[cur] + (wm * (MT / 2) + i * 16 + lrow) * 32 + kq * 8);
#pragma unroll
            for (int j = 0; j < FN; j++)
                bv[j] = *(const bf16x8*)(Bs[cur] + (wn * (NT / 2) + j * 16 + lrow) * 32 + kq * 8);
#pragma unroll
            for (int i = 0; i < FM; i++)
#pragma unroll
                for (int j = 0; j < FN; j++)
                    acc[i][j] = __builtin_amdgcn_mfma_f32_16x16x32_bf16(av[i], bv[j], acc[i][j], 0, 0, 0);
            asm volatile("" ::: "memory");   // pin next-iter stage below this barrier
            __builtin_amdgcn_s_barrier();
        }
    } else {
        for (int k0 = 0; k0 < K; k0 += 32) {
#pragma unroll
            for (int p = 0; p < (MT * 64) / 4096; p++) {
                int idx = p * 256 + tid, row = idx >> 2, ch = idx & 3;
                gll16(A + (size_t)row * lda + k0 + ch * 8, As[0] + idx * 8);
            }
            {
                const float* Wk = (W2_ && k0 >= ga.ksplit) ? W2_ + (size_t)(k0 - ga.ksplit) * ldb
                                                           : W1_ + (size_t)k0 * ldb;
#pragma unroll
                for (int p = 0; p < NT / 32; p++) {
                    int u = p * 256 + tid;
                    int k = u >> 5, nb = u & 31;
                    float4 w = *(const float4*)(Wk + (size_t)k * ldb + nb * 4);
                    Bs[0][(nb * 4 + 0) * 32 + k] = f2bf(w.x);
                    Bs[0][(nb * 4 + 1) * 32 + k] = f2bf(w.y);
                    Bs[0][(nb * 4 + 2) * 32 + k] = f2bf(w.z);
                    Bs[0][(nb * 4 + 3) * 32 + k] = f2bf(w.w);
                }
            }
            __syncthreads();
            bf16x8 av[FM], bv[FN];
#pragma unroll
            for (int i = 0; i < FM; i++)
                av[i] = *(const bf16x8*)(As[0] + (wm * (MT / 2) + i * 16 + lrow) * 32 + kq * 8);
#pragma unroll
            for (int j = 0; j < FN; j++)
                bv[j] = *(const bf16x8*)(Bs[0] + (wn * (NT / 2) + j * 16 + lrow) * 32 + kq * 8);
#pragma unroll
            for (int i = 0; i < FM; i++)
#pragma unroll
                for (int j = 0; j < FN; j++)
                    acc[i][j] = __builtin_amdgcn_mfma_f32_16x16x32_bf16(av[i], bv[j], acc[i][j], 0, 0, 0);
            __syncthreads();
        }
    }

    const float* b1 = ga.bias1 ? ga.bias1 + (size_t)dir * ga.b1s : nullptr;
    const float* b2 = ga.bias2 ? ga.bias2 + (size_t)dir * ga.b2s : nullptr;
#pragma unroll
    for (int fm = 0; fm < FM; fm++) {
#pragma unroll
        for (int fn = 0; fn < FN; fn++) {
#pragma unroll
            for (int r2 = 0; r2 < 4; r2++) {
                int row = rowbase + wm * (MT / 2) + fm * 16 + kq * 4 + r2;
                int col = colbase + wn * (NT / 2) + fn * 16 + lrow;
                float v = acc[fm][fn][r2];
                if constexpr (MODE == 0) {
                    v += b1[col] + b2[col];
                    if (col < 1536) v = v > 0.f ? v + 1.f : __expf(v);
                    ga.obf[(size_t)row * 2304 + col] = f2bf(v);
                } else if constexpr (MODE == 1) {
                    ga.obf[(size_t)row * 768 + col] = f2bf(v);
                } else if constexpr (MODE == 2) {
                    v += b1[col];
                    int b = (row >> 10) & 1, n = row & 1023;
                    int t = (row >> 11) ? ga.tB : ga.tF;
                    float pos = ga.temp[(size_t)(b * Ln + t) * Dn + col] *
                                ga.spat[(size_t)(b * Nn + n) * Dn + col];
                    size_t xi = ((size_t)(b * Ln + t) * Nn + n) * Dn + col;
                    float xv = (ga.xf ? ga.xf[xi] : bf2f(ga.xb[xi])) + pos;
                    ga.x2[(size_t)row * Dn + col] = v + xv;
                    ga.hbuf[(size_t)row * Dn + col] += v;
                } else if constexpr (MODE == 3) {
                    v += b1[col];
                    v = 0.5f * v * (1.f + erff(v * 0.7071067811865475f));
                    ga.obf[(size_t)row * 3072 + col] = f2bf(v);
                } else {
                    v += b1[col] + ga.x2[(size_t)row * Dn + col];
                    int b = (row >> 10) & 1, n = row & 1023;
                    int t = (row >> 11) ? ga.tB : ga.tF;
                    size_t oi = ((size_t)(b * Ln + t) * Nn + n) * Dn + col;
                    if (ga.yf) {
                        if (ga.store_flag) ga.yf[oi] = v;
                        else ga.yf[oi] += v;
                    } else {
                        if (ga.store_flag) ga.yb[oi] = f2bf(v);
                        else ga.yb[oi] = f2bf(v + bf2f(ga.yb[oi]));
                    }
                }
            }
        }
    }
}

// ---------------- kv einsum ----------------
__global__ void __launch_bounds__(256) kv_partial_kernel(const u16* __restrict__ qkv,
                                                         float* __restrict__ part)
{
    int combo = blockIdx.x, js = blockIdx.y;
    int g4 = combo / 12, h = combo - g4 * 12;
    int d0 = (threadIdx.x & 15) * 4, e0 = (threadIdx.x >> 4) * 4;
    const u16* base = qkv + ((size_t)g4 * 1024 + js * 128) * 2304 + 768 + h * 64;
    float acc[4][4] = {};
#pragma unroll 4
    for (int j = 0; j < 128; j++) {
        const u16* kp = base + (size_t)j * 2304 + d0;
        const u16* vp = base + (size_t)j * 2304 + 768 + e0;
        ushort4 kk = *(const ushort4*)kp;
        ushort4 vv = *(const ushort4*)vp;
        float kd[4] = {bf2f(kk.x), bf2f(kk.y), bf2f(kk.z), bf2f(kk.w)};
        float ve[4] = {bf2f(vv.x), bf2f(vv.y), bf2f(vv.z), bf2f(vv.w)};
#pragma unroll
        for (int di = 0; di < 4; di++)
#pragma unroll
            for (int ei = 0; ei < 4; ei++) acc[di][ei] += kd[di] * ve[ei];
    }
    float* pp = part + ((size_t)js * 48 + combo) * 4096;
#pragma unroll
    for (int di = 0; di < 4; di++)
#pragma unroll
        for (int ei = 0; ei < 4; ei++)
            pp[(e0 + ei) * 64 + (d0 + di)] = acc[di][ei];   // kv^T: [e][d]
}

__global__ void __launch_bounds__(256) kv_reduce_kernel(const float* __restrict__ part,
                                                        u16* __restrict__ kvT)
{
    int combo = blockIdx.x;
    for (int idx = threadIdx.x; idx < 4096; idx += 256) {
        float s = 0.f;
#pragma unroll
        for (int js = 0; js < 8; js++) s += part[((size_t)js * 48 + combo) * 4096 + idx];
        kvT[(size_t)combo * 4096 + idx] = f2bf(s);
    }
}

// ---------------- weight transpose (fp32 -> bf16 B^T) ----------------
__global__ void transpose_kernel(const float* __restrict__ src, u16* __restrict__ dst,
                                 int K, int N, int ldd, int dcol)
{
    __shared__ float tile[32][33];
    int n0 = blockIdx.x * 32, k0 = blockIdx.y * 32;
    int tx = threadIdx.x, ty = threadIdx.y;   // (32,8)
#pragma unroll
    for (int i = 0; i < 4; i++) {
        int k = k0 + ty + i * 8;
        tile[ty + i * 8][tx] = src[(size_t)k * N + n0 + tx];
    }
    __syncthreads();
#pragma unroll
    for (int i = 0; i < 4; i++) {
        int n = n0 + ty + i * 8;
        dst[(size_t)n * ldd + dcol + k0 + tx] = f2bf(tile[tx][ty + i * 8]);
    }
}

__global__ void __launch_bounds__(256) init_h_kernel(const float* __restrict__ hidden,
                                                     float* __restrict__ hbuf)
{
    unsigned i = blockIdx.x * 256u + threadIdx.x;   // 4*1024*768
    unsigned d = i % 768u;
    unsigned r = i / 768u;
    unsigned b = (r >> 10) & 1u, n = r & 1023u;
    hbuf[i] = hidden[((size_t)b * 1024 + n) * 768 + d];
}

// ---------------- host ----------------
extern "C" void kernel_launch(void* const* d_in, const int* in_sizes, int n_in,
                              void* d_out, int out_size, void* d_ws, size_t ws_size,
                              hipStream_t stream)
{
    (void)in_sizes; (void)n_in; (void)out_size;
    const float* xin    = (const float*)d_in[0];
    const float* hidden = (const float*)d_in[1];
    const float* spat   = (const float*)d_in[2];
    const float* temp   = (const float*)d_in[3];
    const float* lig    = (const float*)d_in[4];
    const float* lib_   = (const float*)d_in[5];
    const float* lhg    = (const float*)d_in[6];
    const float* lhb    = (const float*)d_in[7];
    const float* log_   = (const float*)d_in[8];
    const float* lob    = (const float*)d_in[9];
    const float* Wqkv   = (const float*)d_in[10];
    const float* bqkv   = (const float*)d_in[11];
    const float* Wqkvh  = (const float*)d_in[12];
    const float* bqkvh  = (const float*)d_in[13];
    const float* Wout   = (const float*)d_in[14];
    const float* bout   = (const float*)d_in[15];
    const float* W1     = (const float*)d_in[16];
    const float* b1     = (const float*)d_in[17];
    const float* W2     = (const float*)d_in[18];
    const float* b2     = (const float*)d_in[19];

    char* w = (char*)d_ws;
    float* hbuf  = (float*)(w + 0);              // 12,582,912 B
    float* x2    = (float*)(w + 12582912);       // 12,582,912 B
    u16*   xC    = (u16*)(w + 25165824);         // 37,748,736 B (bf16 layer-0 output)
    u16*   kvT   = (u16*)(w + 62914560);         //    393,216 B
    u16*   regA  = (u16*)(w + 63307776);         // 12,582,912 B
    u16*   regB  = (u16*)(w + 75890688);         // 25,165,824 B  -> base end 101,056,512
    u16*   qkvTc = (u16*)(w + 101056512);        // 14,155,776 B
    u16*   woutTc= (u16*)(w + 115212288);        //  2,359,296 B
    u16*   w1Tc  = (u16*)(w + 117571584);        //  9,437,184 B
    u16*   w2Tc  = (u16*)(w + 127008768);        //  9,437,184 B  -> 136,445,952
    const bool cached = ws_size >= 136445952ull;

    u16*   acat  = regA;
    float* kvp   = (float*)regA;                 // alias after acat dead
    u16*   obf   = regA;                         // alias after kvp dead
    u16*   ln2b  = regA + 3145728;               // second half of regA
    u16*   qkvb  = regB;
    u16*   mlp1b = regB;

    dim3 tb(32, 8);
    for (int l = 0; l < 2; l++) {
        if (cached) {
            for (int dir = 0; dir < 2; dir++) {
                int s4 = dir * 2 + l;
                transpose_kernel<<<dim3(72, 24), tb, 0, stream>>>(
                    Wqkv + (size_t)s4 * 768 * 2304, qkvTc + (size_t)dir * 2304 * 1536, 768, 2304, 1536, 0);
                transpose_kernel<<<dim3(72, 24), tb, 0, stream>>>(
                    Wqkvh + (size_t)s4 * 768 * 2304, qkvTc + (size_t)dir * 2304 * 1536, 768, 2304, 1536, 768);
                transpose_kernel<<<dim3(24, 24), tb, 0, stream>>>(
                    Wout + (size_t)s4 * 768 * 768, woutTc + (size_t)dir * 768 * 768, 768, 768, 768, 0);
                transpose_kernel<<<dim3(96, 24), tb, 0, stream>>>(
                    W1 + (size_t)s4 * 768 * 3072, w1Tc + (size_t)dir * 3072 * 768, 768, 3072, 768, 0);
                transpose_kernel<<<dim3(24, 96), tb, 0, stream>>>(
                    W2 + (size_t)s4 * 3072 * 768, w2Tc + (size_t)dir * 768 * 3072, 3072, 768, 3072, 0);
            }
        }
        init_h_kernel<<<12288, 256, 0, stream>>>(hidden, hbuf);
        const float* xsf = l ? nullptr : xin;
        const u16*   xsb = l ? xC : nullptr;
        float* yf = l ? (float*)d_out : nullptr;
        u16*   yb = l ? nullptr : xC;
        for (int s = 0; s < 12; s++) {
            int tF = s, tB = 11 - s;
            ln1_kernel<<<1024, 256, 0, stream>>>(xsf, xsb, hbuf, temp, spat, lig, lib_, lhg, lhb,
                                                 acat, l, tF, tB);
            {   // QKV  (MT=128: 576 blocks, 2.25/CU — proven best)
                GArgs g{};
                g.A = acat; g.lda = 1536; g.K = 1536;
                g.bias1 = bqkv + (size_t)l * 2304; g.b1s = 2 * 2304;
                g.bias2 = bqkvh + (size_t)l * 2304; g.b2s = 2 * 2304;
                g.obf = qkvb;
                if (cached) {
                    g.BT = qkvTc; g.bstride = 2304ll * 1536; g.ldb = 1536;
                    gemm_kernel<128, 128, 0, true><<<dim3(16, 18, 2), 256, 0, stream>>>(g);
                } else {
                    g.Wf = Wqkv + (size_t)l * 768 * 2304;
                    g.Wf2 = Wqkvh + (size_t)l * 768 * 2304;
                    g.wstride = 2ll * 768 * 2304; g.ksplit = 768; g.ldb = 2304;
                    gemm_kernel<128, 128, 0, false><<<dim3(16, 18, 2), 256, 0, stream>>>(g);
                }
            }
            kv_partial_kernel<<<dim3(48, 8), 256, 0, stream>>>(qkvb, kvp);
            kv_reduce_kernel<<<48, 256, 0, stream>>>(kvp, kvT);
            {   // O = q . kv
                GArgs g{};
                g.A = qkvb; g.BT = kvT; g.obf = obf;
                gemm_kernel<128, 64, 1, true><<<dim3(8, 48, 1), 256, 0, stream>>>(g);
            }
            {   // attn out + residual + hidden update  (MT=64: 384 blocks, 1.5/CU)
                GArgs g{};
                g.A = obf; g.lda = 768; g.K = 768;
                g.bias1 = bout + (size_t)l * 768; g.b1s = 2 * 768;
                g.xf = xsf; g.xb = xsb; g.temp = temp; g.spat = spat; g.x2 = x2; g.hbuf = hbuf;
                g.tF = tF; g.tB = tB;
                if (cached) {
                    g.BT = woutTc; g.bstride = 768ll * 768; g.ldb = 768;
                    gemm_kernel<64, 128, 2, true><<<dim3(32, 6, 2), 256, 0, stream>>>(g);
                } else {
                    g.Wf = Wout + (size_t)l * 768 * 768; g.wstride = 2ll * 768 * 768;
                    g.ldb = 768; g.ksplit = g.K;
                    gemm_kernel<64, 128, 2, false><<<dim3(32, 6, 2), 256, 0, stream>>>(g);
                }
            }
            ln2_kernel<<<1024, 256, 0, stream>>>(x2, log_, lob, ln2b, l);
            {   // MLP1  (MT=128: 768 blocks, 3/CU — proven best)
                GArgs g{};
                g.A = ln2b; g.lda = 768; g.K = 768;
                g.bias1 = b1 + (size_t)l * 3072; g.b1s = 2 * 3072;
                g.obf = mlp1b;
                if (cached) {
                    g.BT = w1Tc; g.bstride = 3072ll * 768; g.ldb = 768;
                    gemm_kernel<128, 128, 3, true><<<dim3(16, 24, 2), 256, 0, stream>>>(g);
                } else {
                    g.Wf = W1 + (size_t)l * 768 * 3072; g.wstride = 2ll * 768 * 3072;
                    g.ldb = 3072; g.ksplit = g.K;
                    gemm_kernel<128, 128, 3, false><<<dim3(16, 24, 2), 256, 0, stream>>>(g);
                }
            }
            {   // MLP2 + residual -> y accumulate  (MT=64: 384 blocks, 1.5/CU)
                GArgs g{};
                g.A = mlp1b; g.lda = 3072; g.K = 3072;
                g.bias1 = b2 + (size_t)l * 768; g.b1s = 2 * 768;
                g.x2 = x2; g.yf = yf; g.yb = yb; g.store_flag = (s <= 5) ? 1 : 0;
                g.tF = tF; g.tB = tB;
                if (cached) {
                    g.BT = w2Tc; g.bstride = 768ll * 3072; g.ldb = 3072;
                    gemm_kernel<64, 128, 4, true><<<dim3(32, 6, 2), 256, 0, stream>>>(g);
                } else {
                    g.Wf = W2 + (size_t)l * 3072 * 768; g.wstride = 2ll * 3072 * 768;
                    g.ldb = 768; g.ksplit = g.K;
                    gemm_kernel<64, 128, 4, false><<<dim3(32, 6, 2), 256, 0, stream>>>(g);
                }
            }
        }
    }
}